// Round 4
// baseline (442.190 us; speedup 1.0000x reference)
//
#include <hip/hip_runtime.h>
#include <hip/hip_bf16.h>
#include <math.h>

#define N_NODES    100000
#define N_PATHS    1600000
#define PATH_SZ    3
#define IN_SZ      64
#define HID        32
#define EMB_STRIDE 96          // PATH_SZ * HID
#define EPS_F      1e-4f

#define SCAN_TPB   256
#define SCAN_IPT   8
#define SCAN_CHUNK (SCAN_TPB * SCAN_IPT)                        // 2048
#define SCAN_NB    ((N_NODES + SCAN_CHUNK - 1) / SCAN_CHUNK)   // 49

// ---- static device scratch (avoids any ws_size assumptions) ----
__device__ float g_emb[(size_t)N_NODES * EMB_STRIDE];  // 38.4 MB
__device__ float g_M[HID * HID];                       // gram^{-1/2}
__device__ int   g_offs[N_NODES];
__device__ int   g_bsum[SCAN_NB];
__device__ int   g_boff[SCAN_NB];

// ---------------- prefix-sum of kernel_size -> g_offs ----------------
__global__ __launch_bounds__(SCAN_TPB) void k_scan1(const int* __restrict__ ksz) {
    __shared__ int red[SCAN_TPB];
    int b = blockIdx.x, t = threadIdx.x;
    int base = b * SCAN_CHUNK + t * SCAN_IPT;
    int s = 0;
#pragma unroll
    for (int u = 0; u < SCAN_IPT; u++) {
        int idx = base + u;
        if (idx < N_NODES) s += ksz[idx];
    }
    red[t] = s;
    __syncthreads();
    for (int d = SCAN_TPB >> 1; d > 0; d >>= 1) {
        if (t < d) red[t] += red[t + d];
        __syncthreads();
    }
    if (t == 0) g_bsum[b] = red[0];
}

__global__ void k_scan2() {
    if (threadIdx.x == 0) {
        int run = 0;
        for (int b = 0; b < SCAN_NB; b++) { g_boff[b] = run; run += g_bsum[b]; }
    }
}

__global__ __launch_bounds__(SCAN_TPB) void k_scan3(const int* __restrict__ ksz) {
    __shared__ int sc[SCAN_TPB];
    int b = blockIdx.x, t = threadIdx.x;
    int base = b * SCAN_CHUNK + t * SCAN_IPT;
    int v[SCAN_IPT];
    int s = 0;
#pragma unroll
    for (int u = 0; u < SCAN_IPT; u++) {
        int idx = base + u;
        v[u] = (idx < N_NODES) ? ksz[idx] : 0;
        s += v[u];
    }
    sc[t] = s;
    __syncthreads();
    // Hillis-Steele inclusive scan over 256 thread sums
    for (int d = 1; d < SCAN_TPB; d <<= 1) {
        int a = (t >= d) ? sc[t - d] : 0;
        __syncthreads();
        sc[t] += a;
        __syncthreads();
    }
    int incl = sc[t];
    int run = g_boff[b] + (incl - s);   // exclusive prefix for this thread
#pragma unroll
    for (int u = 0; u < SCAN_IPT; u++) {
        int idx = base + u;
        if (idx < N_NODES) g_offs[idx] = run;
        run += v[u];
    }
}

// ---------------- fused: emb GEMM (blocks>=1) + gram/Jacobi/inv-sqrt (block 0) ----------------
union ShK1 {
    struct { float stage[4][64 * 33]; } e;                           // 33792 B
    struct {
        float w[96 * 65];            // padded weight copy
        float A[32 * 33];
        float V[32 * 33];
        float c[16], s[16];
        int   p[16], q[16];
        float lamInv[32];
    } j;
};

__global__ __launch_bounds__(256) void k_emb_jac(const float* __restrict__ feat,
                                                 const float* __restrict__ W) {
    __shared__ ShK1 sh;
    int t = threadIdx.x;

    if (blockIdx.x == 0) {
        // ---- stage weight into LDS (padded rows) ----
        for (int idx = t; idx < 96 * 64; idx += 256) {
            int r = idx >> 6, c = idx & 63;
            sh.j.w[r * 65 + c] = W[idx];
        }
        __syncthreads();
        // ---- gram = kappa(W·Wt / 3), V = I ----
#pragma unroll
        for (int u = 0; u < 4; u++) {
            int e = t * 4 + u;
            int h = e >> 5, g = e & 31;
            float d = 0.f;
            for (int pi = 0; pi < 3; pi++) {
                const float* r0 = &sh.j.w[(h * 3 + pi) * 65];
                const float* r1 = &sh.j.w[(g * 3 + pi) * 65];
#pragma unroll
                for (int i = 0; i < 64; i++) d = fmaf(r0[i], r1[i], d);
            }
            sh.j.A[h * 33 + g] = __expf(fmaf(d, 4.0f / 3.0f, -4.0f));
            sh.j.V[h * 33 + g] = (h == g) ? 1.0f : 0.0f;
        }
        __syncthreads();
        // ---- cyclic Jacobi, parallel (round-robin) ordering, 6 sweeps ----
        for (int sweep = 0; sweep < 6; sweep++) {
            for (int r = 0; r < 31; r++) {
                if (t < 16) {
                    int p, q;
                    if (t == 0) { p = 31; q = r; }
                    else { p = (r + t) % 31; q = (r + 31 - t) % 31; }
                    if (p > q) { int tmp = p; p = q; q = tmp; }
                    float app = sh.j.A[p * 33 + p];
                    float aqq = sh.j.A[q * 33 + q];
                    float apq = sh.j.A[p * 33 + q];
                    float c = 1.f, s = 0.f;
                    if (fabsf(apq) > 1e-30f) {
                        float tau = (aqq - app) / (2.f * apq);
                        float tt = 1.f / (fabsf(tau) + sqrtf(1.f + tau * tau));
                        tt = copysignf(tt, tau);
                        c = 1.f / sqrtf(1.f + tt * tt);
                        s = tt * c;
                    }
                    sh.j.c[t] = c; sh.j.s[t] = s; sh.j.p[t] = p; sh.j.q[t] = q;
                }
                __syncthreads();
                // row phase: rows p,q  (JtA)
                {
                    int item = t;           // 0..255 then +256
#pragma unroll
                    for (int rep = 0; rep < 2; rep++) {
                        int k = item >> 5, jcol = item & 31;
                        int p = sh.j.p[k], q = sh.j.q[k];
                        float c = sh.j.c[k], s = sh.j.s[k];
                        float ap = sh.j.A[p * 33 + jcol];
                        float aq = sh.j.A[q * 33 + jcol];
                        sh.j.A[p * 33 + jcol] = c * ap - s * aq;
                        sh.j.A[q * 33 + jcol] = s * ap + c * aq;
                        item += 256;
                    }
                }
                __syncthreads();
                // col phase: cols p,q  ((JtA)J) + eigenvector update V <- V J
                {
                    int item = t;
#pragma unroll
                    for (int rep = 0; rep < 2; rep++) {
                        int k = item >> 5, jrow = item & 31;
                        int p = sh.j.p[k], q = sh.j.q[k];
                        float c = sh.j.c[k], s = sh.j.s[k];
                        float ap = sh.j.A[jrow * 33 + p];
                        float aq = sh.j.A[jrow * 33 + q];
                        sh.j.A[jrow * 33 + p] = c * ap - s * aq;
                        sh.j.A[jrow * 33 + q] = s * ap + c * aq;
                        float vp = sh.j.V[jrow * 33 + p];
                        float vq = sh.j.V[jrow * 33 + q];
                        sh.j.V[jrow * 33 + p] = c * vp - s * vq;
                        sh.j.V[jrow * 33 + q] = s * vp + c * vq;
                        item += 256;
                    }
                }
                __syncthreads();
            }
        }
        if (t < 32) sh.j.lamInv[t] = 1.0f / sqrtf(fmaxf(sh.j.A[t * 33 + t], EPS_F));
        __syncthreads();
        // M = V diag(lamInv) Vt
#pragma unroll
        for (int u = 0; u < 4; u++) {
            int e = t * 4 + u;
            int i = e >> 5, j = e & 31;
            float m = 0.f;
#pragma unroll
            for (int k = 0; k < 32; k++)
                m = fmaf(sh.j.V[i * 33 + k] * sh.j.lamInv[k], sh.j.V[j * 33 + k], m);
            g_M[e] = m;
        }
        return;
    }

    // ---------------- emb path: one node per thread ----------------
    int nb = blockIdx.x - 1;
    int wave = t >> 6, lane = t & 63;
    int n = nb * 256 + t;
    int n0w = nb * 256 + wave * 64;
    bool act = (n < N_NODES);

    float x[64];
    if (act) {
        const float4* f4 = reinterpret_cast<const float4*>(feat + (size_t)n * 64);
#pragma unroll
        for (int c = 0; c < 16; c++) {
            float4 v = f4[c];
            x[c * 4 + 0] = v.x; x[c * 4 + 1] = v.y; x[c * 4 + 2] = v.z; x[c * 4 + 3] = v.w;
        }
    } else {
#pragma unroll
        for (int i = 0; i < 64; i++) x[i] = 0.f;
    }
    float ssum = 0.f;
#pragma unroll
    for (int i = 0; i < 64; i++) ssum = fmaf(x[i], x[i], ssum);
    float nrm = fmaxf(sqrtf(ssum), EPS_F);
    float inv = 1.0f / nrm;

#pragma unroll 1
    for (int p = 0; p < 3; p++) {
#pragma unroll 4
        for (int h = 0; h < HID; h++) {
            const float* wr = W + (h * 3 + p) * 64;   // wave-uniform address -> scalar loads
            float a = 0.f;
#pragma unroll
            for (int i = 0; i < 64; i++) a = fmaf(x[i], wr[i], a);
            sh.e.stage[wave][lane * 33 + h] = a * inv;
        }
        __syncthreads();
#pragma unroll 4
        for (int r = 0; r < 32; r++) {
            int f = r * 64 + lane;
            int nl = f >> 5, h = f & 31;
            int n2 = n0w + nl;
            if (n2 < N_NODES)
                g_emb[(size_t)n2 * EMB_STRIDE + p * HID + h] = sh.e.stage[wave][nl * 33 + h];
        }
        __syncthreads();
    }
}

// ---------------- gather + kappa + segment-sum + whiten ----------------
__global__ __launch_bounds__(256) void k_pool(const int* __restrict__ paths,
                                              const int* __restrict__ ksz,
                                              float* __restrict__ out) {
    __shared__ float Ml[HID * HID];
    for (int idx = threadIdx.x; idx < HID * HID; idx += 256) Ml[idx] = g_M[idx];
    __syncthreads();

    int lane = threadIdx.x & 63;
    int half = lane >> 5;
    int j = lane & 31;
    int wid = blockIdx.x * 4 + (threadIdx.x >> 6);
    int nwaves = gridDim.x * 4;

    for (int node = wid; node < N_NODES; node += nwaves) {
        int off = g_offs[node];
        int ks  = ksz[node];
        float pooled = 0.f;
        int iters = (ks + 1) >> 1;
        for (int tt = 0; tt < iters; tt++) {
            int pi = tt * 2 + half;
            if (pi < ks) {
                size_t pp = (size_t)(off + pi) * 3;
                int i0 = paths[pp + 0];
                int i1 = paths[pp + 1];
                int i2 = paths[pp + 2];
                float e = g_emb[(size_t)i0 * EMB_STRIDE + j]
                        + g_emb[(size_t)i1 * EMB_STRIDE + HID + j]
                        + g_emb[(size_t)i2 * EMB_STRIDE + 2 * HID + j];
                pooled += __expf(fmaf(e, 4.0f / 3.0f, -4.0f));
            }
        }
        pooled += __shfl_xor(pooled, 32);   // combine the two half-waves
        // whiten: out[node][j] = sum_k pooled[k] * M[k][j]
        float o = 0.f;
#pragma unroll
        for (int k = 0; k < 32; k++)
            o = fmaf(__shfl(pooled, k), Ml[k * 32 + j], o);
        if (half == 0) out[(size_t)node * HID + j] = o;
    }
}

extern "C" void kernel_launch(void* const* d_in, const int* in_sizes, int n_in,
                              void* d_out, int out_size, void* d_ws, size_t ws_size,
                              hipStream_t stream) {
    const float* feat  = (const float*)d_in[0];
    const int*   paths = (const int*)d_in[1];
    const int*   ksz   = (const int*)d_in[2];
    const float* W     = (const float*)d_in[3];
    float*       out   = (float*)d_out;

    k_scan1<<<SCAN_NB, SCAN_TPB, 0, stream>>>(ksz);
    k_scan2<<<1, 64, 0, stream>>>();
    k_scan3<<<SCAN_NB, SCAN_TPB, 0, stream>>>(ksz);

    int embBlocks = (N_NODES + 255) / 256;          // 391
    k_emb_jac<<<embBlocks + 1, 256, 0, stream>>>(feat, W);

    k_pool<<<2048, 256, 0, stream>>>(paths, ksz, out);
}

// Round 5
// 301.376 us; speedup vs baseline: 1.4672x; 1.4672x over previous
//
#include <hip/hip_runtime.h>
#include <hip/hip_fp16.h>
#include <math.h>

#define N_NODES    100000
#define N_PATHS    1600000
#define PATH_SZ    3
#define IN_SZ      64
#define HID        32
#define EMB_STRIDE 96          // PATH_SZ * HID (halves)
#define EPS_F      1e-4f

#define SCAN_TPB   256
#define SCAN_IPT   8
#define SCAN_CHUNK (SCAN_TPB * SCAN_IPT)                        // 2048
#define SCAN_NB    ((N_NODES + SCAN_CHUNK - 1) / SCAN_CHUNK)   // 49

// ---- static device scratch ----
__device__ __half g_embh[(size_t)N_NODES * EMB_STRIDE];  // 19.2 MB fp16
__device__ float  g_M[HID * HID];                        // gram^{-1/2}
__device__ int    g_offs[N_NODES];
__device__ int    g_bsum[SCAN_NB];
__device__ int    g_boff[SCAN_NB];

// ---------------- prefix-sum of kernel_size -> g_offs ----------------
__global__ __launch_bounds__(SCAN_TPB) void k_scan1(const int* __restrict__ ksz) {
    __shared__ int red[SCAN_TPB];
    int b = blockIdx.x, t = threadIdx.x;
    int base = b * SCAN_CHUNK + t * SCAN_IPT;
    int s = 0;
#pragma unroll
    for (int u = 0; u < SCAN_IPT; u++) {
        int idx = base + u;
        if (idx < N_NODES) s += ksz[idx];
    }
    red[t] = s;
    __syncthreads();
    for (int d = SCAN_TPB >> 1; d > 0; d >>= 1) {
        if (t < d) red[t] += red[t + d];
        __syncthreads();
    }
    if (t == 0) g_bsum[b] = red[0];
}

__global__ void k_scan2() {
    if (threadIdx.x == 0) {
        int run = 0;
        for (int b = 0; b < SCAN_NB; b++) { g_boff[b] = run; run += g_bsum[b]; }
    }
}

__global__ __launch_bounds__(SCAN_TPB) void k_scan3(const int* __restrict__ ksz) {
    __shared__ int sc[SCAN_TPB];
    int b = blockIdx.x, t = threadIdx.x;
    int base = b * SCAN_CHUNK + t * SCAN_IPT;
    int v[SCAN_IPT];
    int s = 0;
#pragma unroll
    for (int u = 0; u < SCAN_IPT; u++) {
        int idx = base + u;
        v[u] = (idx < N_NODES) ? ksz[idx] : 0;
        s += v[u];
    }
    sc[t] = s;
    __syncthreads();
    for (int d = 1; d < SCAN_TPB; d <<= 1) {
        int a = (t >= d) ? sc[t - d] : 0;
        __syncthreads();
        sc[t] += a;
        __syncthreads();
    }
    int incl = sc[t];
    int run = g_boff[b] + (incl - s);
#pragma unroll
    for (int u = 0; u < SCAN_IPT; u++) {
        int idx = base + u;
        if (idx < N_NODES) g_offs[idx] = run;
        run += v[u];
    }
}

// ---------------- fused: emb GEMM (blocks>=1) + gram/Newton-Schulz (block 0) ----------------
// NS replaces Jacobi: G = I + E, off-diag ~ e^-4 => spectrum in ~[0.97,1.56],
// ||I-G|| ~ 0.56 => 6 coupled NS iters converge to fp32 precision, Z -> G^{-1/2}.
struct ShJ {
    float w[96 * 65];    // padded weight copy (24.96 KB)
    float Y[32 * 33];
    float Z[32 * 33];
    float P[32 * 33];
};

__global__ __launch_bounds__(256) void k_emb_ns(const float* __restrict__ feat,
                                                const float* __restrict__ W) {
    __shared__ ShJ sh;
    int t = threadIdx.x;

    if (blockIdx.x == 0) {
        // stage weight into LDS (padded rows)
        for (int idx = t; idx < 96 * 64; idx += 256) {
            int r = idx >> 6, c = idx & 63;
            sh.w[r * 65 + c] = W[idx];
        }
        __syncthreads();
        // G into Y; Z = I
#pragma unroll
        for (int u = 0; u < 4; u++) {
            int e = t * 4 + u;
            int h = e >> 5, g = e & 31;
            float d = 0.f;
            for (int pi = 0; pi < 3; pi++) {
                const float* r0 = &sh.w[(h * 3 + pi) * 65];
                const float* r1 = &sh.w[(g * 3 + pi) * 65];
#pragma unroll
                for (int i = 0; i < 64; i++) d = fmaf(r0[i], r1[i], d);
            }
            sh.Y[h * 33 + g] = __expf(fmaf(d, 4.0f / 3.0f, -4.0f));
            sh.Z[h * 33 + g] = (h == g) ? 1.0f : 0.0f;
        }
        __syncthreads();
        // coupled Newton-Schulz: P = Z*Y; T = (3I-P)/2; Y <- Y*T; Z <- T*Z
        for (int it = 0; it < 6; it++) {
#pragma unroll
            for (int u = 0; u < 4; u++) {
                int e = t * 4 + u;
                int i = e >> 5, j = e & 31;
                float p = 0.f;
#pragma unroll
                for (int k = 0; k < 32; k++)
                    p = fmaf(sh.Z[i * 33 + k], sh.Y[k * 33 + j], p);
                sh.P[i * 33 + j] = p;
            }
            __syncthreads();
            float U[4], V[4];
#pragma unroll
            for (int u = 0; u < 4; u++) {
                int e = t * 4 + u;
                int i = e >> 5, j = e & 31;
                float su = 0.f, sv = 0.f;
#pragma unroll
                for (int k = 0; k < 32; k++) {
                    float Tkj = -0.5f * sh.P[k * 33 + j]; if (k == j) Tkj += 1.5f;
                    float Tik = -0.5f * sh.P[i * 33 + k]; if (i == k) Tik += 1.5f;
                    su = fmaf(sh.Y[i * 33 + k], Tkj, su);
                    sv = fmaf(Tik, sh.Z[k * 33 + j], sv);
                }
                U[u] = su; V[u] = sv;
            }
            __syncthreads();
#pragma unroll
            for (int u = 0; u < 4; u++) {
                int e = t * 4 + u;
                int i = e >> 5, j = e & 31;
                sh.Y[i * 33 + j] = U[u];
                sh.Z[i * 33 + j] = V[u];
            }
            __syncthreads();
        }
#pragma unroll
        for (int u = 0; u < 4; u++) {
            int e = t * 4 + u;
            g_M[e] = sh.Z[(e >> 5) * 33 + (e & 31)];
        }
        return;
    }

    // ---------------- emb path: one node per thread, direct fp16 stores ----------------
    int n = (blockIdx.x - 1) * 256 + t;
    if (n >= N_NODES) return;           // no barriers below

    float x[64];
    const float4* f4 = reinterpret_cast<const float4*>(feat + (size_t)n * 64);
#pragma unroll
    for (int c = 0; c < 16; c++) {
        float4 v = f4[c];
        x[c * 4 + 0] = v.x; x[c * 4 + 1] = v.y; x[c * 4 + 2] = v.z; x[c * 4 + 3] = v.w;
    }
    float ssum = 0.f;
#pragma unroll
    for (int i = 0; i < 64; i++) ssum = fmaf(x[i], x[i], ssum);
    float inv = 1.0f / fmaxf(sqrtf(ssum), EPS_F);

#pragma unroll 1
    for (int p = 0; p < 3; p++) {
        __half hv[32];
#pragma unroll 4
        for (int h = 0; h < HID; h++) {
            const float* wr = W + (h * 3 + p) * 64;   // wave-uniform -> scalar loads
            float a = 0.f;
#pragma unroll
            for (int i = 0; i < 64; i++) a = fmaf(x[i], wr[i], a);
            hv[h] = __float2half(a * inv);
        }
        // 64 B contiguous store
        const int4* src = reinterpret_cast<const int4*>(hv);
        int4* dst = reinterpret_cast<int4*>(&g_embh[(size_t)n * EMB_STRIDE + p * HID]);
#pragma unroll
        for (int c = 0; c < 4; c++) dst[c] = src[c];
    }
}

// ---------------- gather + kappa + segment-sum + whiten ----------------
__global__ __launch_bounds__(256) void k_pool(const int* __restrict__ paths,
                                              const int* __restrict__ ksz,
                                              float* __restrict__ out) {
    __shared__ float Ml[HID * HID];
    for (int idx = threadIdx.x; idx < HID * HID; idx += 256) Ml[idx] = g_M[idx];
    __syncthreads();

    int lane = threadIdx.x & 63;
    int half = lane >> 5;
    int j = lane & 31;
    int wid = blockIdx.x * 4 + (threadIdx.x >> 6);
    int nwaves = gridDim.x * 4;
    const __half* eb = g_embh;

    for (int node = wid; node < N_NODES; node += nwaves) {
        int off = g_offs[node];
        int ks  = ksz[node];
        float a0 = 0.f, a1 = 0.f;
        int s4 = ks >> 2;                       // 4 paths per step (2 per half-wave)
        for (int s = 0; s < s4; s++) {
            int pa = s * 4 + half * 2;
            size_t pp = (size_t)(off + pa) * 3;
            int iA0 = paths[pp + 0], iA1 = paths[pp + 1], iA2 = paths[pp + 2];
            int iB0 = paths[pp + 3], iB1 = paths[pp + 4], iB2 = paths[pp + 5];
            float eA = __half2float(eb[(size_t)iA0 * EMB_STRIDE + j])
                     + __half2float(eb[(size_t)iA1 * EMB_STRIDE + HID + j])
                     + __half2float(eb[(size_t)iA2 * EMB_STRIDE + 2 * HID + j]);
            float eB = __half2float(eb[(size_t)iB0 * EMB_STRIDE + j])
                     + __half2float(eb[(size_t)iB1 * EMB_STRIDE + HID + j])
                     + __half2float(eb[(size_t)iB2 * EMB_STRIDE + 2 * HID + j]);
            a0 += __expf(fmaf(eA, 4.0f / 3.0f, -4.0f));
            a1 += __expf(fmaf(eB, 4.0f / 3.0f, -4.0f));
        }
        // tail (ks not multiple of 4)
        for (int pi = s4 * 4 + half; pi < ks; pi += 2) {
            size_t pp = (size_t)(off + pi) * 3;
            int i0 = paths[pp + 0], i1 = paths[pp + 1], i2 = paths[pp + 2];
            float e = __half2float(eb[(size_t)i0 * EMB_STRIDE + j])
                    + __half2float(eb[(size_t)i1 * EMB_STRIDE + HID + j])
                    + __half2float(eb[(size_t)i2 * EMB_STRIDE + 2 * HID + j]);
            a0 += __expf(fmaf(e, 4.0f / 3.0f, -4.0f));
        }
        float pooled = a0 + a1;
        pooled += __shfl_xor(pooled, 32);       // combine the two half-waves
        // whiten: out[node][j] = sum_k pooled[k] * M[k][j]
        float o = 0.f;
#pragma unroll
        for (int k = 0; k < 32; k++)
            o = fmaf(__shfl(pooled, k), Ml[k * 32 + j], o);
        if (half == 0) out[(size_t)node * HID + j] = o;
    }
}

extern "C" void kernel_launch(void* const* d_in, const int* in_sizes, int n_in,
                              void* d_out, int out_size, void* d_ws, size_t ws_size,
                              hipStream_t stream) {
    const float* feat  = (const float*)d_in[0];
    const int*   paths = (const int*)d_in[1];
    const int*   ksz   = (const int*)d_in[2];
    const float* W     = (const float*)d_in[3];
    float*       out   = (float*)d_out;

    k_scan1<<<SCAN_NB, SCAN_TPB, 0, stream>>>(ksz);
    k_scan2<<<1, 64, 0, stream>>>();
    k_scan3<<<SCAN_NB, SCAN_TPB, 0, stream>>>(ksz);

    int embBlocks = (N_NODES + 255) / 256;          // 391
    k_emb_ns<<<embBlocks + 1, 256, 0, stream>>>(feat, W);

    k_pool<<<2048, 256, 0, stream>>>(paths, ksz, out);
}